// Round 1
// baseline (308.711 us; speedup 1.0000x reference)
//
#include <hip/hip_runtime.h>

typedef _Float16 half8 __attribute__((ext_vector_type(8)));
typedef float f32x4 __attribute__((ext_vector_type(4)));

#define MFMA16(a, b, c) __builtin_amdgcn_mfma_f32_16x16x32_f16((a), (b), (c), 0, 0, 0)

// ---------------------------------------------------------------- constants
// B=2, N=2048, C=1024, H=16, D=64; M = B*N = 4096 tokens.
// qkv buffer layout: [s][b][h][n][d], s-stride = 2*16*2048*64 = 4194304 elems.

// ---------------------------------------------------------------- fp32 -> fp16
__global__ __launch_bounds__(256) void cvt_f32_f16(const float* __restrict__ in,
                                                   _Float16* __restrict__ out, int n8) {
    int i = blockIdx.x * 256 + threadIdx.x;
    if (i >= n8) return;
    const float4* p = reinterpret_cast<const float4*>(in) + 2 * (size_t)i;
    float4 a = p[0], b = p[1];
    half8 o;
    o[0] = (_Float16)a.x; o[1] = (_Float16)a.y; o[2] = (_Float16)a.z; o[3] = (_Float16)a.w;
    o[4] = (_Float16)b.x; o[5] = (_Float16)b.y; o[6] = (_Float16)b.z; o[7] = (_Float16)b.w;
    reinterpret_cast<half8*>(out)[i] = o;
}

// ---------------------------------------------------------------- GEMM (NT): C[m][n] = sum_k A[m][k]*W[n][k] + bias[n]
// EPI 0: scatter to qkv fp16 [s][b][h][n][d];  EPI 1: fp32 out [m][n].
template <int EPI>
__global__ __launch_bounds__(256) void gemm_nt(const _Float16* __restrict__ A,
                                               const _Float16* __restrict__ W,
                                               const float* __restrict__ bias,
                                               void* __restrict__ Cout, int K) {
    __shared__ __align__(16) _Float16 Al[128 * 72];
    __shared__ __align__(16) _Float16 Wl[128 * 72];
    const int tid = threadIdx.x, l = tid & 63, w = tid >> 6;
    const int bm = blockIdx.x * 128, bn = blockIdx.y * 128;
    const int wr = (w >> 1) * 64, wc = (w & 1) * 64;
    const int row_s = tid >> 3, col8 = (tid & 7) * 8;

    f32x4 acc[4][4] = {};
    for (int kt = 0; kt < K; kt += 64) {
        __syncthreads();
#pragma unroll
        for (int r = 0; r < 4; r++) {
            int row = row_s + r * 32;
            half8 av = *(const half8*)&A[(size_t)(bm + row) * K + kt + col8];
            half8 wv = *(const half8*)&W[(size_t)(bn + row) * K + kt + col8];
            *(half8*)&Al[row * 72 + col8] = av;
            *(half8*)&Wl[row * 72 + col8] = wv;
        }
        __syncthreads();
#pragma unroll
        for (int ks = 0; ks < 2; ks++) {
            const int koff = ks * 32 + (l >> 4) * 8;
            half8 af[4], wf[4];
#pragma unroll
            for (int t = 0; t < 4; t++) {
                af[t] = *(const half8*)&Al[(wr + t * 16 + (l & 15)) * 72 + koff];
                wf[t] = *(const half8*)&Wl[(wc + t * 16 + (l & 15)) * 72 + koff];
            }
#pragma unroll
            for (int mt = 0; mt < 4; mt++)
#pragma unroll
                for (int nt = 0; nt < 4; nt++)
                    acc[mt][nt] = MFMA16(af[mt], wf[nt], acc[mt][nt]);
        }
    }
#pragma unroll
    for (int mt = 0; mt < 4; mt++)
#pragma unroll
        for (int nt = 0; nt < 4; nt++)
#pragma unroll
            for (int r = 0; r < 4; r++) {
                int m = bm + wr + mt * 16 + (l >> 4) * 4 + r;
                int n = bn + wc + nt * 16 + (l & 15);
                float v = acc[mt][nt][r] + bias[n];
                if (EPI == 0) {
                    int s = n >> 10, h = (n >> 6) & 15, d = n & 63;
                    int b = m >> 11, nn = m & 2047;
                    ((_Float16*)Cout)[(size_t)((((s * 2 + b) * 16 + h) * 2048 + nn) << 6) + d] =
                        (_Float16)v;
                } else {
                    ((float*)Cout)[(size_t)m * 1024 + n] = v;
                }
            }
}

// ---------------------------------------------------------------- per-head LayerNorm on q,k (rows of 64)
__global__ __launch_bounds__(256) void ln_qk(_Float16* __restrict__ qkv,
                                             const float* __restrict__ qg,
                                             const float* __restrict__ qb,
                                             const float* __restrict__ kg,
                                             const float* __restrict__ kb) {
    const int l = threadIdx.x & 63, w = threadIdx.x >> 6;
    const int rid = blockIdx.x * 4 + w;  // [0, 131072)
    const int s = rid >> 16;             // 0 = q, 1 = k
    _Float16* base = qkv + (size_t)s * 4194304 + (size_t)(rid & 65535) * 64;
    float x = (float)base[l];
    float sm = x, s2 = x * x;
#pragma unroll
    for (int off = 1; off < 64; off <<= 1) {
        sm += __shfl_xor(sm, off);
        s2 += __shfl_xor(s2, off);
    }
    float mean = sm * (1.f / 64.f);
    float var = s2 * (1.f / 64.f) - mean * mean;
    float rs = rsqrtf(var + 1e-5f);
    float g = s ? kg[l] : qg[l];
    float be = s ? kb[l] : qb[l];
    base[l] = (_Float16)((x - mean) * rs * g + be);
}

// ---------------------------------------------------------------- flash attention
// grid 512: blockIdx = head*16 + qtile.  4 waves, 32 q-rows each (128-row Q tile).
__global__ __launch_bounds__(256) void attn_kernel(const _Float16* __restrict__ qkv,
                                                   _Float16* __restrict__ out) {
    const int tid = threadIdx.x, l = tid & 63, w = tid >> 6;
    const int head = blockIdx.x >> 4, qt = blockIdx.x & 15;
    const int b = head >> 4, h = head & 15;
    const size_t hstride = (size_t)2048 * 64;
    const _Float16* Q = qkv + (size_t)((0 + b) * 16 + h) * hstride;
    const _Float16* Kp = qkv + (size_t)((2 + b) * 16 + h) * hstride;
    const _Float16* Vp = qkv + (size_t)((4 + b) * 16 + h) * hstride;

    __shared__ __align__(16) _Float16 Kl[64 * 72];
    __shared__ __align__(16) char Vt[64 * 144];  // [d][j] fp16, XOR-swizzled cols
    __shared__ __align__(16) _Float16 Pl[128 * 72];

    const int r0 = qt * 128 + w * 32;
    half8 qf[2][2];
#pragma unroll
    for (int mt = 0; mt < 2; mt++)
#pragma unroll
        for (int ks = 0; ks < 2; ks++)
            qf[mt][ks] =
                *(const half8*)&Q[(size_t)(r0 + mt * 16 + (l & 15)) * 64 + ks * 32 + (l >> 4) * 8];

    float mrun[2][4], lrun[2][4];
    f32x4 accO[2][4] = {};
#pragma unroll
    for (int mt = 0; mt < 2; mt++)
#pragma unroll
        for (int r = 0; r < 4; r++) {
            mrun[mt][r] = -1e30f;
            lrun[mt][r] = 0.f;
        }

    const int jrow = tid >> 3, d0 = (tid & 7) * 8;
    const int vswz = (tid & 7) << 4;  // ((d>>3)&7)<<4, d0 = (tid&7)*8
    _Float16* Pw = Pl + w * 32 * 72;

    for (int it = 0; it < 32; it++) {
        __syncthreads();
#pragma unroll
        for (int r = 0; r < 2; r++) {
            int j = jrow + r * 32;
            half8 kv = *(const half8*)&Kp[(size_t)(it * 64 + j) * 64 + d0];
            *(half8*)&Kl[j * 72 + d0] = kv;
            half8 vv = *(const half8*)&Vp[(size_t)(it * 64 + j) * 64 + d0];
#pragma unroll
            for (int i = 0; i < 8; i++) {
                int d = d0 + i;
                *(_Float16*)(Vt + d * 144 + ((2 * j) ^ vswz)) = vv[i];
            }
        }
        __syncthreads();

        // S = Q K^T  (16x64 per m-tile)
        f32x4 sacc[2][4] = {};
#pragma unroll
        for (int ks = 0; ks < 2; ks++) {
            const int koff = ks * 32 + (l >> 4) * 8;
            half8 kf[4];
#pragma unroll
            for (int nt = 0; nt < 4; nt++)
                kf[nt] = *(const half8*)&Kl[(nt * 16 + (l & 15)) * 72 + koff];
#pragma unroll
            for (int mt = 0; mt < 2; mt++)
#pragma unroll
                for (int nt = 0; nt < 4; nt++)
                    sacc[mt][nt] = MFMA16(qf[mt][ks], kf[nt], sacc[mt][nt]);
        }

        // online softmax per row (row = mt*16 + (l>>4)*4 + r, cols nt*16 + (l&15))
#pragma unroll
        for (int mt = 0; mt < 2; mt++)
#pragma unroll
            for (int r = 0; r < 4; r++) {
                float s0 = sacc[mt][0][r] * 0.125f, s1 = sacc[mt][1][r] * 0.125f;
                float s2 = sacc[mt][2][r] * 0.125f, s3 = sacc[mt][3][r] * 0.125f;
                float mx = fmaxf(fmaxf(s0, s1), fmaxf(s2, s3));
                mx = fmaxf(mx, __shfl_xor(mx, 1));
                mx = fmaxf(mx, __shfl_xor(mx, 2));
                mx = fmaxf(mx, __shfl_xor(mx, 4));
                mx = fmaxf(mx, __shfl_xor(mx, 8));
                float mold = mrun[mt][r];
                float mnew = fmaxf(mold, mx);
                float alpha = __expf(mold - mnew);
                float p0 = __expf(s0 - mnew), p1 = __expf(s1 - mnew);
                float p2 = __expf(s2 - mnew), p3 = __expf(s3 - mnew);
                float ps = p0 + p1 + p2 + p3;
                ps += __shfl_xor(ps, 1);
                ps += __shfl_xor(ps, 2);
                ps += __shfl_xor(ps, 4);
                ps += __shfl_xor(ps, 8);
                mrun[mt][r] = mnew;
                lrun[mt][r] = lrun[mt][r] * alpha + ps;
#pragma unroll
                for (int dt = 0; dt < 4; dt++) accO[mt][dt][r] *= alpha;
                int wrow = mt * 16 + (l >> 4) * 4 + r;
                Pw[wrow * 72 + 0 + (l & 15)] = (_Float16)p0;
                Pw[wrow * 72 + 16 + (l & 15)] = (_Float16)p1;
                Pw[wrow * 72 + 32 + (l & 15)] = (_Float16)p2;
                Pw[wrow * 72 + 48 + (l & 15)] = (_Float16)p3;
            }

        // O += P V   (A-frags from Pl, B-frags from swizzled Vt)
#pragma unroll
        for (int ks = 0; ks < 2; ks++) {
            const int koff = ks * 32 + (l >> 4) * 8;
            half8 pf[2], vf[4];
#pragma unroll
            for (int mt = 0; mt < 2; mt++)
                pf[mt] = *(const half8*)&Pw[(mt * 16 + (l & 15)) * 72 + koff];
#pragma unroll
            for (int dt = 0; dt < 4; dt++) {
                int d = dt * 16 + (l & 15);
                vf[dt] = *(const half8*)(Vt + d * 144 + ((2 * koff) ^ (((d >> 3) & 7) << 4)));
            }
#pragma unroll
            for (int mt = 0; mt < 2; mt++)
#pragma unroll
                for (int dt = 0; dt < 4; dt++)
                    accO[mt][dt] = MFMA16(pf[mt], vf[dt], accO[mt][dt]);
        }
    }

    // epilogue: normalize rows, write fp16 [b][n][h*64+d]
#pragma unroll
    for (int mt = 0; mt < 2; mt++)
#pragma unroll
        for (int dt = 0; dt < 4; dt++)
#pragma unroll
            for (int r = 0; r < 4; r++) {
                int n = r0 + mt * 16 + (l >> 4) * 4 + r;
                int d = dt * 16 + (l & 15);
                float v = accO[mt][dt][r] / lrun[mt][r];
                out[(size_t)(b * 2048 + n) * 1024 + h * 64 + d] = (_Float16)v;
            }
}

// ---------------------------------------------------------------- launch
extern "C" void kernel_launch(void* const* d_in, const int* in_sizes, int n_in,
                              void* d_out, int out_size, void* d_ws, size_t ws_size,
                              hipStream_t stream) {
    const float* x = (const float*)d_in[0];
    const float* w_qkv = (const float*)d_in[1];
    const float* b_qkv = (const float*)d_in[2];
    const float* q_gamma = (const float*)d_in[3];
    const float* q_beta = (const float*)d_in[4];
    const float* k_gamma = (const float*)d_in[5];
    const float* k_beta = (const float*)d_in[6];
    const float* w_proj = (const float*)d_in[7];
    const float* b_proj = (const float*)d_in[8];

    char* ws = (char*)d_ws;
    _Float16* xh = (_Float16*)(ws + 0);             // 4096*1024
    _Float16* wqkvh = (_Float16*)(ws + 8388608);    // 3072*1024
    _Float16* wprojh = (_Float16*)(ws + 14680064);  // 1024*1024
    _Float16* qkvh = (_Float16*)(ws + 16777216);    // 3*2*16*2048*64
    _Float16* attnh = (_Float16*)(ws + 41943040);   // 4096*1024

    cvt_f32_f16<<<2048, 256, 0, stream>>>(x, xh, 524288);
    cvt_f32_f16<<<1536, 256, 0, stream>>>(w_qkv, wqkvh, 393216);
    cvt_f32_f16<<<512, 256, 0, stream>>>(w_proj, wprojh, 131072);

    gemm_nt<0><<<dim3(32, 24), 256, 0, stream>>>(xh, wqkvh, b_qkv, (void*)qkvh, 1024);

    ln_qk<<<32768, 256, 0, stream>>>(qkvh, q_gamma, q_beta, k_gamma, k_beta);

    attn_kernel<<<512, 256, 0, stream>>>(qkvh, attnh);

    gemm_nt<1><<<dim3(32, 8), 256, 0, stream>>>(attnh, wprojh, b_proj, d_out, 1024);
}

// Round 2
// 252.882 us; speedup vs baseline: 1.2208x; 1.2208x over previous
//
#include <hip/hip_runtime.h>

typedef _Float16 half8 __attribute__((ext_vector_type(8)));
typedef _Float16 half4 __attribute__((ext_vector_type(4)));
typedef float f32x4 __attribute__((ext_vector_type(4)));
typedef float f32x16 __attribute__((ext_vector_type(16)));
typedef unsigned int uint;
typedef uint uint4v __attribute__((ext_vector_type(4)));

#define MFMA16(a, b, c) __builtin_amdgcn_mfma_f32_16x16x32_f16((a), (b), (c), 0, 0, 0)
#define MFMA32(a, b, c) __builtin_amdgcn_mfma_f32_32x32x16_f16((a), (b), (c), 0, 0, 0)

// async global->LDS, 16B per lane, dest = wave-uniform base + lane*16
#define GLOAD16(g, l)                                            \
    __builtin_amdgcn_global_load_lds(                            \
        (const __attribute__((address_space(1))) void*)(g),      \
        (__attribute__((address_space(3))) void*)(l), 16, 0, 0)

// B=2, N=2048, C=1024, H=16, D=64; M = B*N = 4096 tokens.
// qkv buffer layout: [s][b][h][n][d], s-stride = 2*16*2048*64 = 4194304 elems.

// ---------------------------------------------------------------- fp32 -> fp16
__global__ __launch_bounds__(256) void cvt_f32_f16(const float* __restrict__ in,
                                                   _Float16* __restrict__ out, int n8) {
    int i = blockIdx.x * 256 + threadIdx.x;
    if (i >= n8) return;
    const float4* p = reinterpret_cast<const float4*>(in) + 2 * (size_t)i;
    float4 a = p[0], b = p[1];
    half8 o;
    o[0] = (_Float16)a.x; o[1] = (_Float16)a.y; o[2] = (_Float16)a.z; o[3] = (_Float16)a.w;
    o[4] = (_Float16)b.x; o[5] = (_Float16)b.y; o[6] = (_Float16)b.z; o[7] = (_Float16)b.w;
    reinterpret_cast<half8*>(out)[i] = o;
}

// ---------------------------------------------------------------- GEMM (NT), m97 structure:
// 128x128 tile, BK=64, global_load_lds staging, XOR-swizzled linear LDS.
// C[m][n] = sum_k A[m][k]*W[n][k] + bias[n]
// EPI 0: scatter to qkv fp16 [s][b][h][n][d];  EPI 1: fp32 out [m][n].
template <int EPI>
__global__ __launch_bounds__(256) void gemm_nt(const _Float16* __restrict__ A,
                                               const _Float16* __restrict__ W,
                                               const float* __restrict__ bias,
                                               void* __restrict__ Cout, int K) {
    __shared__ __align__(16) _Float16 Al[128 * 64];
    __shared__ __align__(16) _Float16 Wl[128 * 64];
    const int tid = threadIdx.x, l = tid & 63, w = tid >> 6;
    const int bm = blockIdx.x * 128, bn = blockIdx.y * 128;
    const int wr = (w >> 1) * 64, wc = (w & 1) * 64;
    const int srow = l >> 3;                 // 0..7
    const int schunk = (l & 7) ^ srow;       // pre-swizzled source 16B-chunk (rule #21)

    f32x4 acc[4][4] = {};
    const _Float16* Ag = A + (size_t)(bm + 32 * w + srow) * K + 8 * schunk;
    const _Float16* Wg = W + (size_t)(bn + 32 * w + srow) * K + 8 * schunk;
    const int rswz = (l & 7) << 3;           // read-side XOR (halfs), row&7 == l&7 for all frags

    for (int kt = 0; kt < K; kt += 64) {
        __syncthreads();
#pragma unroll
        for (int t = 0; t < 4; t++) {
            GLOAD16(Ag + (size_t)(8 * t) * K + kt, &Al[(32 * w + 8 * t) * 64]);
            GLOAD16(Wg + (size_t)(8 * t) * K + kt, &Wl[(32 * w + 8 * t) * 64]);
        }
        __syncthreads();
#pragma unroll
        for (int ks = 0; ks < 2; ks++) {
            const int koff = (ks * 32 + (l >> 4) * 8) ^ rswz;
            half8 af[4], wf[4];
#pragma unroll
            for (int t = 0; t < 4; t++) {
                af[t] = *(const half8*)&Al[(wr + t * 16 + (l & 15)) * 64 + koff];
                wf[t] = *(const half8*)&Wl[(wc + t * 16 + (l & 15)) * 64 + koff];
            }
#pragma unroll
            for (int mt = 0; mt < 4; mt++)
#pragma unroll
                for (int nt = 0; nt < 4; nt++)
                    acc[mt][nt] = MFMA16(af[mt], wf[nt], acc[mt][nt]);
        }
    }
#pragma unroll
    for (int mt = 0; mt < 4; mt++)
#pragma unroll
        for (int nt = 0; nt < 4; nt++)
#pragma unroll
            for (int r = 0; r < 4; r++) {
                int m = bm + wr + mt * 16 + (l >> 4) * 4 + r;
                int n = bn + wc + nt * 16 + (l & 15);
                float v = acc[mt][nt][r] + bias[n];
                if (EPI == 0) {
                    int s = n >> 10, h = (n >> 6) & 15, d = n & 63;
                    int b = m >> 11, nn = m & 2047;
                    ((_Float16*)Cout)[(size_t)((((s * 2 + b) * 16 + h) * 2048 + nn) << 6) + d] =
                        (_Float16)v;
                } else {
                    ((float*)Cout)[(size_t)m * 1024 + n] = v;
                }
            }
}

// ---------------------------------------------------------------- per-head LayerNorm on q,k (rows of 64)
__global__ __launch_bounds__(256) void ln_qk(_Float16* __restrict__ qkv,
                                             const float* __restrict__ qg,
                                             const float* __restrict__ qb,
                                             const float* __restrict__ kg,
                                             const float* __restrict__ kb) {
    const int l = threadIdx.x & 63, w = threadIdx.x >> 6;
    const int rid = blockIdx.x * 4 + w;  // [0, 131072)
    const int s = rid >> 16;             // 0 = q, 1 = k
    _Float16* base = qkv + (size_t)s * 4194304 + (size_t)(rid & 65535) * 64;
    float x = (float)base[l];
    float sm = x, s2 = x * x;
#pragma unroll
    for (int off = 1; off < 64; off <<= 1) {
        sm += __shfl_xor(sm, off);
        s2 += __shfl_xor(s2, off);
    }
    float mean = sm * (1.f / 64.f);
    float var = s2 * (1.f / 64.f) - mean * mean;
    float rs = rsqrtf(var + 1e-5f);
    float g = s ? kg[l] : qg[l];
    float be = s ? kb[l] : qb[l];
    base[l] = (_Float16)((x - mean) * rs * g + be);
}

// ---------------------------------------------------------------- flash attention, swapped-QK^T 32x32
// grid 512: blockIdx = head*16 + qtile. 4 waves x 32 q-rows = 128-row Q tile, KVBLK=64.
// S^T = mfma(Kfrag, Qfrag): lane owns column q = lane&31, 32 k-values in regs.
// O^T = mfma(Vfrag, Pfrag): lane owns column q; rescale alpha is a lane scalar.
__global__ __launch_bounds__(256) void attn_kernel(const _Float16* __restrict__ qkv,
                                                   _Float16* __restrict__ out) {
    const int tid = threadIdx.x;
    const int l = tid & 63, w = tid >> 6;
    const int l31 = l & 31, hi = l >> 5;
    const int head = blockIdx.x >> 4, qt = blockIdx.x & 15;
    const int b = head >> 4, h = head & 15;
    const size_t hstride = (size_t)2048 * 64;
    const _Float16* Q = qkv + (size_t)((0 + b) * 16 + h) * hstride;
    const _Float16* Kp = qkv + (size_t)((2 + b) * 16 + h) * hstride;
    const _Float16* Vp = qkv + (size_t)((4 + b) * 16 + h) * hstride;

    __shared__ __align__(16) _Float16 Kl[2][64 * 64];  // [k][d], slot ^= (k&7)
    __shared__ __align__(16) _Float16 Vt[2][64 * 64];  // [d][k], slot ^= (d&7)^((d>>3)&7)

    // ---- Q fragments (B-operand): Q[q=l31][d = 16*dk + 8*hi + i], pre-scaled by 0.125
    const int r0q = qt * 128 + w * 32;
    half8 qf[4];
    {
        const _Float16* Qrow = Q + (size_t)(r0q + l31) * 64 + 8 * hi;
#pragma unroll
        for (int dk = 0; dk < 4; dk++) {
            half8 v = *(const half8*)&Qrow[16 * dk];
#pragma unroll
            for (int i = 0; i < 8; i++) v[i] = v[i] * (_Float16)0.125f;
            qf[dk] = v;
        }
    }

    const int srow = l >> 3, sch = l & 7;
    // K staging: wave w covers rows 16w..16w+15; source chunk pre-swizzled so LDS reads XOR back.
    auto stageK = [&](int it, _Float16* dst) {
#pragma unroll
        for (int t = 0; t < 2; t++) {
            int r0 = 16 * w + 8 * t;
            const _Float16* g = Kp + (size_t)(it * 64 + r0 + srow) * 64 + 8 * (sch ^ srow);
            GLOAD16(g, &dst[r0 * 64]);
        }
    };
    auto loadV = [&](int it, half8& v0, half8& v1) {
        const _Float16* g = Vp + (size_t)(it * 64 + 16 * w + srow) * 64 + 8 * sch;
        v0 = *(const half8*)g;
        v1 = *(const half8*)(g + 8 * 64);
    };
    // transpose-scatter V -> Vt[d][k]; write banks 2-way (free), reads optimal
    auto scatterV = [&](half8 v0, half8 v1, _Float16* dst) {
        const int j0 = 16 * w + srow;
        const int d0 = 8 * sch;
#pragma unroll
        for (int i = 0; i < 8; i++) {
            const int sw = (i ^ sch) << 3;
            dst[(d0 + i) * 64 + (j0 ^ sw)] = v0[i];
            dst[(d0 + i) * 64 + ((j0 + 8) ^ sw)] = v1[i];
        }
    };

    float mrun = -1e30f, lrun = 0.f;
    f32x16 o0 = {}, o1 = {};

    half8 va, vb;
    stageK(0, Kl[0]);
    loadV(0, va, vb);
    scatterV(va, vb, Vt[0]);
    __syncthreads();

    const int kswz = (l31 & 7) << 3;
    const int vswz0 = ((l31 & 7) ^ (l31 >> 3)) << 3;
    const int vswz1 = vswz0 ^ (4 << 3);

    for (int it = 0; it < 32; ++it) {
        const int cur = it & 1;
        const _Float16* Kc = Kl[cur];
        const _Float16* Vc = Vt[cur];
        if (it + 1 < 32) {
            stageK(it + 1, Kl[cur ^ 1]);  // async, in flight across compute
            loadV(it + 1, va, vb);        // T14 issue-early
        }
        // ---- S^T = K Q^T : st0 = k rows 0..31, st1 = 32..63
        f32x16 st0 = {}, st1 = {};
#pragma unroll
        for (int dk = 0; dk < 4; dk++) {
            const int colr = 16 * dk + 8 * hi;
            half8 kf0 = *(const half8*)&Kc[l31 * 64 + (colr ^ kswz)];
            half8 kf1 = *(const half8*)&Kc[(32 + l31) * 64 + (colr ^ kswz)];
            st0 = MFMA32(kf0, qf[dk], st0);
            st1 = MFMA32(kf1, qf[dk], st1);
        }
        // ---- online softmax: lane owns column q = l31; partner lane l^32 has other half offsets
        float mh = st0[0];
#pragma unroll
        for (int r = 1; r < 16; r++) mh = fmaxf(mh, st0[r]);
#pragma unroll
        for (int r = 0; r < 16; r++) mh = fmaxf(mh, st1[r]);
        mh = fmaxf(mh, __shfl_xor(mh, 32));
        const float mnew = fmaxf(mrun, mh);
        const float alpha = __expf(mrun - mnew);
        mrun = mnew;
        float lh = 0.f;
#pragma unroll
        for (int r = 0; r < 16; r++) { st0[r] = __expf(st0[r] - mnew); lh += st0[r]; }
#pragma unroll
        for (int r = 0; r < 16; r++) { st1[r] = __expf(st1[r] - mnew); lh += st1[r]; }
        lh += __shfl_xor(lh, 32);
        lrun = lrun * alpha + lh;
#pragma unroll
        for (int r = 0; r < 16; r++) { o0[r] *= alpha; o1[r] *= alpha; }

        // ---- P fragments in-register (cvt_pkrtz + shfl_xor(32)) + PV
        // lane holds P^T[k=crow(r,hi)][q]; A-frag needs P[q][k=16c+8hi+i].
#define PV_CHUNK(stv, c)                                                                   \
        {                                                                                  \
            uint pk0 = __builtin_bit_cast(uint, __builtin_amdgcn_cvt_pkrtz(stv[(c & 1) * 8 + 0], stv[(c & 1) * 8 + 1])); \
            uint pk1 = __builtin_bit_cast(uint, __builtin_amdgcn_cvt_pkrtz(stv[(c & 1) * 8 + 2], stv[(c & 1) * 8 + 3])); \
            uint pk2 = __builtin_bit_cast(uint, __builtin_amdgcn_cvt_pkrtz(stv[(c & 1) * 8 + 4], stv[(c & 1) * 8 + 5])); \
            uint pk3 = __builtin_bit_cast(uint, __builtin_amdgcn_cvt_pkrtz(stv[(c & 1) * 8 + 6], stv[(c & 1) * 8 + 7])); \
            uint sa = __shfl_xor(pk0, 32), sb = __shfl_xor(pk1, 32);                       \
            uint sc = __shfl_xor(pk2, 32), sd = __shfl_xor(pk3, 32);                       \
            uint4v fu = {hi ? sc : pk0, hi ? sd : pk1, hi ? pk2 : sa, hi ? pk3 : sb};      \
            half8 pfrag = __builtin_bit_cast(half8, fu);                                   \
            const int colc = 16 * (c) + 8 * hi;                                            \
            half8 vf0 = *(const half8*)&Vc[l31 * 64 + (colc ^ vswz0)];                     \
            half8 vf1 = *(const half8*)&Vc[(32 + l31) * 64 + (colc ^ vswz1)];              \
            o0 = MFMA32(vf0, pfrag, o0);                                                   \
            o1 = MFMA32(vf1, pfrag, o1);                                                   \
        }
        PV_CHUNK(st0, 0)
        PV_CHUNK(st0, 1)
        PV_CHUNK(st1, 2)
        PV_CHUNK(st1, 3)
#undef PV_CHUNK

        if (it + 1 < 32) scatterV(va, vb, Vt[cur ^ 1]);
        __syncthreads();
    }

    // ---- epilogue: O^T[d][q] -> out[b][tok][h*64+d], d = 32*mt + 8*g + 4*hi + j
    const float inv = __builtin_amdgcn_rcpf(lrun);
    const int tok = r0q + l31;
    _Float16* orow = out + (size_t)(b * 2048 + tok) * 1024 + h * 64;
#pragma unroll
    for (int g = 0; g < 4; g++) {
        half4 h4a, h4b;
#pragma unroll
        for (int j = 0; j < 4; j++) {
            h4a[j] = (_Float16)(o0[4 * g + j] * inv);
            h4b[j] = (_Float16)(o1[4 * g + j] * inv);
        }
        *(half4*)&orow[8 * g + 4 * hi] = h4a;
        *(half4*)&orow[32 + 8 * g + 4 * hi] = h4b;
    }
}

// ---------------------------------------------------------------- launch
extern "C" void kernel_launch(void* const* d_in, const int* in_sizes, int n_in,
                              void* d_out, int out_size, void* d_ws, size_t ws_size,
                              hipStream_t stream) {
    const float* x = (const float*)d_in[0];
    const float* w_qkv = (const float*)d_in[1];
    const float* b_qkv = (const float*)d_in[2];
    const float* q_gamma = (const float*)d_in[3];
    const float* q_beta = (const float*)d_in[4];
    const float* k_gamma = (const float*)d_in[5];
    const float* k_beta = (const float*)d_in[6];
    const float* w_proj = (const float*)d_in[7];
    const float* b_proj = (const float*)d_in[8];

    char* ws = (char*)d_ws;
    _Float16* xh = (_Float16*)(ws + 0);             // 4096*1024
    _Float16* wqkvh = (_Float16*)(ws + 8388608);    // 3072*1024
    _Float16* wprojh = (_Float16*)(ws + 14680064);  // 1024*1024
    _Float16* qkvh = (_Float16*)(ws + 16777216);    // 3*2*16*2048*64
    _Float16* attnh = (_Float16*)(ws + 41943040);   // 4096*1024

    cvt_f32_f16<<<2048, 256, 0, stream>>>(x, xh, 524288);
    cvt_f32_f16<<<1536, 256, 0, stream>>>(w_qkv, wqkvh, 393216);
    cvt_f32_f16<<<512, 256, 0, stream>>>(w_proj, wprojh, 131072);

    gemm_nt<0><<<dim3(32, 24), 256, 0, stream>>>(xh, wqkvh, b_qkv, (void*)qkvh, 1024);

    ln_qk<<<32768, 256, 0, stream>>>(qkvh, q_gamma, q_beta, k_gamma, k_beta);

    attn_kernel<<<512, 256, 0, stream>>>(qkvh, attnh);

    gemm_nt<1><<<dim3(32, 8), 256, 0, stream>>>(attnh, wprojh, b_proj, d_out, 1024);
}

// Round 3
// 223.254 us; speedup vs baseline: 1.3828x; 1.1327x over previous
//
#include <hip/hip_runtime.h>

typedef _Float16 half8 __attribute__((ext_vector_type(8)));
typedef _Float16 half4 __attribute__((ext_vector_type(4)));
typedef float f32x4 __attribute__((ext_vector_type(4)));
typedef float f32x16 __attribute__((ext_vector_type(16)));
typedef unsigned int uint;
typedef uint uint4v __attribute__((ext_vector_type(4)));

#define MFMA16(a, b, c) __builtin_amdgcn_mfma_f32_16x16x32_f16((a), (b), (c), 0, 0, 0)
#define MFMA32(a, b, c) __builtin_amdgcn_mfma_f32_32x32x16_f16((a), (b), (c), 0, 0, 0)

// async global->LDS, 16B per lane, dest = wave-uniform base + lane*16
#define GLOAD16(g, l)                                            \
    __builtin_amdgcn_global_load_lds(                            \
        (const __attribute__((address_space(1))) void*)(g),      \
        (__attribute__((address_space(3))) void*)(l), 16, 0, 0)

// B=2, N=2048, C=1024, H=16, D=64; M = B*N = 4096 tokens.
// qkv buffer layout: [s][b][h][n][d], s-stride = 2*16*2048*64 = 4194304 elems.
// q rows are stored LN'd AND pre-scaled by 0.125*log2(e) (folded into gemm1 epilogue, f32).

// ---------------------------------------------------------------- fused fp32 -> fp16 (x, w_qkv, w_proj)
__global__ __launch_bounds__(256) void cvt_all(const float* __restrict__ x,
                                               const float* __restrict__ wq,
                                               const float* __restrict__ wp,
                                               _Float16* __restrict__ xh,
                                               _Float16* __restrict__ wqh,
                                               _Float16* __restrict__ wph) {
    int i = blockIdx.x * 256 + threadIdx.x;  // 1,048,576 half8 units
    const float* src;
    _Float16* dst;
    int off;
    if (i < 524288) { src = x; dst = xh; off = i; }
    else if (i < 917504) { src = wq; dst = wqh; off = i - 524288; }
    else { src = wp; dst = wph; off = i - 917504; }
    const float4* p = reinterpret_cast<const float4*>(src) + 2 * (size_t)off;
    float4 a = p[0], b = p[1];
    half8 o;
    o[0] = (_Float16)a.x; o[1] = (_Float16)a.y; o[2] = (_Float16)a.z; o[3] = (_Float16)a.w;
    o[4] = (_Float16)b.x; o[5] = (_Float16)b.y; o[6] = (_Float16)b.z; o[7] = (_Float16)b.w;
    reinterpret_cast<half8*>(dst)[off] = o;
}

// ---------------------------------------------------------------- GEMM (NT), m97 structure:
// 128x128 tile, BK=64, global_load_lds staging, XOR-swizzled linear LDS, XCD-swizzled grid.
// C[m][n] = sum_k A[m][k]*W[n][k] + bias[n]
// EPI 0: fused per-head LayerNorm on q,k + scatter to qkv fp16 [s][b][h][n][d]
//        (q additionally scaled by 0.125*log2e in f32).
// EPI 1: fp32 out [m][n].
template <int EPI>
__global__ __launch_bounds__(256) void gemm_nt(const _Float16* __restrict__ A,
                                               const _Float16* __restrict__ W,
                                               const float* __restrict__ bias,
                                               void* __restrict__ Cout, int K,
                                               const float* __restrict__ qg,
                                               const float* __restrict__ qb,
                                               const float* __restrict__ kg,
                                               const float* __restrict__ kb) {
    __shared__ __align__(16) _Float16 Al[128 * 64];
    __shared__ __align__(16) _Float16 Wl[128 * 64];
    const int tid = threadIdx.x, l = tid & 63, w = tid >> 6;
    // bijective XCD swizzle (gridDim.x == 32 for both instances; nwg % 8 == 0)
    const int lin = blockIdx.x + (blockIdx.y << 5);
    const int nwg = gridDim.x * gridDim.y;
    const int wg = (lin & 7) * (nwg >> 3) + (lin >> 3);
    const int bm = (wg & 31) * 128, bn = (wg >> 5) * 128;
    const int wr = (w >> 1) * 64, wc = (w & 1) * 64;
    const int srow = l >> 3;                 // 0..7
    const int schunk = (l & 7) ^ srow;       // pre-swizzled source 16B-chunk (rule #21)

    f32x4 acc[4][4] = {};
    const _Float16* Ag = A + (size_t)(bm + 32 * w + srow) * K + 8 * schunk;
    const _Float16* Wg = W + (size_t)(bn + 32 * w + srow) * K + 8 * schunk;
    const int rswz = (l & 7) << 3;           // read-side XOR (halfs)

    for (int kt = 0; kt < K; kt += 64) {
        __syncthreads();
#pragma unroll
        for (int t = 0; t < 4; t++) {
            GLOAD16(Ag + (size_t)(8 * t) * K + kt, &Al[(32 * w + 8 * t) * 64]);
            GLOAD16(Wg + (size_t)(8 * t) * K + kt, &Wl[(32 * w + 8 * t) * 64]);
        }
        __syncthreads();
#pragma unroll
        for (int ks = 0; ks < 2; ks++) {
            const int koff = (ks * 32 + (l >> 4) * 8) ^ rswz;
            half8 af[4], wf[4];
#pragma unroll
            for (int t = 0; t < 4; t++) {
                af[t] = *(const half8*)&Al[(wr + t * 16 + (l & 15)) * 64 + koff];
                wf[t] = *(const half8*)&Wl[(wc + t * 16 + (l & 15)) * 64 + koff];
            }
            __builtin_amdgcn_s_setprio(1);
#pragma unroll
            for (int mt = 0; mt < 4; mt++)
#pragma unroll
                for (int nt = 0; nt < 4; nt++)
                    acc[mt][nt] = MFMA16(af[mt], wf[nt], acc[mt][nt]);
            __builtin_amdgcn_s_setprio(0);
        }
    }

    if (EPI == 0) {
        const int ncol = bn + wc;            // 64-aligned -> exactly one (s, head) d-window
        const int s = ncol >> 10;
        const int hh = (ncol >> 6) & 15;
        const float* gam = (s == 0) ? qg : kg;
        const float* bet = (s == 0) ? qb : kb;
        float ga[4], be[4];
        if (s < 2) {
#pragma unroll
            for (int nt = 0; nt < 4; nt++) {
                int d = nt * 16 + (l & 15);
                ga[nt] = gam[d];
                be[nt] = bet[d];
            }
        }
        const float cs = (s == 0) ? 0.18033688f : 1.f;  // 0.125*log2(e) folded into q
#pragma unroll
        for (int mt = 0; mt < 4; mt++)
#pragma unroll
            for (int r = 0; r < 4; r++) {
                float v[4];
                float sm = 0.f, s2 = 0.f;
#pragma unroll
                for (int nt = 0; nt < 4; nt++) {
                    v[nt] = acc[mt][nt][r] + bias[ncol + nt * 16 + (l & 15)];
                    sm += v[nt];
                    s2 += v[nt] * v[nt];
                }
                int m = bm + wr + mt * 16 + (l >> 4) * 4 + r;
                int b = m >> 11, nn = m & 2047;
                _Float16* dst = (_Float16*)Cout +
                    (size_t)((((s * 2 + b) * 16 + hh) * 2048 + nn) << 6);
                if (s < 2) {
#pragma unroll
                    for (int off = 1; off < 16; off <<= 1) {
                        sm += __shfl_xor(sm, off);
                        s2 += __shfl_xor(s2, off);
                    }
                    float mean = sm * (1.f / 64.f);
                    float var = s2 * (1.f / 64.f) - mean * mean;
                    float rs = rsqrtf(var + 1e-5f) * cs;
#pragma unroll
                    for (int nt = 0; nt < 4; nt++) {
                        int d = nt * 16 + (l & 15);
                        dst[d] = (_Float16)((v[nt] - mean) * rs * ga[nt] + be[nt] * cs);
                    }
                } else {
#pragma unroll
                    for (int nt = 0; nt < 4; nt++)
                        dst[nt * 16 + (l & 15)] = (_Float16)v[nt];
                }
            }
    } else {
#pragma unroll
        for (int mt = 0; mt < 4; mt++)
#pragma unroll
            for (int nt = 0; nt < 4; nt++)
#pragma unroll
                for (int r = 0; r < 4; r++) {
                    int m = bm + wr + mt * 16 + (l >> 4) * 4 + r;
                    int n = bn + wc + nt * 16 + (l & 15);
                    ((float*)Cout)[(size_t)m * 1024 + n] = acc[mt][nt][r] + bias[n];
                }
    }
}

// ---------------------------------------------------------------- flash attention, swapped-QK^T 32x32
// grid 512 (XCD-swizzled): wg = head*16 + qtile. 4 waves x 32 q-rows, KVBLK=64.
// No online max: q pre-scaled by 0.125*log2e => s' <= 11.6, p = 2^s' <= 2980 fits fp16.
__global__ __launch_bounds__(256) void attn_kernel(const _Float16* __restrict__ qkv,
                                                   _Float16* __restrict__ out) {
    const int tid = threadIdx.x;
    const int l = tid & 63, w = tid >> 6;
    const int l31 = l & 31, hi = l >> 5;
    const int bid = blockIdx.x;
    const int wg = (bid & 7) * 64 + (bid >> 3);  // 512 = 8*64, bijective XCD chunking
    const int head = wg >> 4, qt = wg & 15;
    const int b = head >> 4, h = head & 15;
    const size_t hstride = (size_t)2048 * 64;
    const _Float16* Q = qkv + (size_t)((0 + b) * 16 + h) * hstride;
    const _Float16* Kp = qkv + (size_t)((2 + b) * 16 + h) * hstride;
    const _Float16* Vp = qkv + (size_t)((4 + b) * 16 + h) * hstride;

    __shared__ __align__(16) _Float16 Kl[2][64 * 64];  // [k][d], chunk ^= (k&7)
    __shared__ __align__(16) _Float16 Vt[2][64 * 64];  // [d][k], slot ^= (d&7)^((d>>3)&7)

    // ---- Q fragments (B-operand): Q[q=l31][d = 16*dk + 8*hi + i] (already LN'd + scaled)
    const int r0q = qt * 128 + w * 32;
    half8 qf[4];
    {
        const _Float16* Qrow = Q + (size_t)(r0q + l31) * 64 + 8 * hi;
#pragma unroll
        for (int dk = 0; dk < 4; dk++) qf[dk] = *(const half8*)&Qrow[16 * dk];
    }

    const int srow = l >> 3, sch = l & 7;
    auto stageK = [&](int it, _Float16* dst) {
#pragma unroll
        for (int t = 0; t < 2; t++) {
            int r0 = 16 * w + 8 * t;
            const _Float16* g = Kp + (size_t)(it * 64 + r0 + srow) * 64 + 8 * (sch ^ srow);
            GLOAD16(g, &dst[r0 * 64]);
        }
    };
    auto loadV = [&](int it, half8& v0, half8& v1) {
        const _Float16* g = Vp + (size_t)(it * 64 + 16 * w + srow) * 64 + 8 * sch;
        v0 = *(const half8*)g;
        v1 = *(const half8*)(g + 8 * 64);
    };
    auto scatterV = [&](half8 v0, half8 v1, _Float16* dst) {
        const int j0 = 16 * w + srow;
        const int d0 = 8 * sch;
#pragma unroll
        for (int i = 0; i < 8; i++) {
            const int sw = (i ^ sch) << 3;
            dst[(d0 + i) * 64 + (j0 ^ sw)] = v0[i];
            dst[(d0 + i) * 64 + ((j0 + 8) ^ sw)] = v1[i];
        }
    };

    float lrun = 0.f;
    f32x16 o0 = {}, o1 = {};

    half8 va, vb;
    stageK(0, Kl[0]);
    loadV(0, va, vb);
    scatterV(va, vb, Vt[0]);
    __syncthreads();

    const int kswz = (l31 & 7) << 3;
    const int vswz0 = ((l31 & 7) ^ (l31 >> 3)) << 3;
    const int vswz1 = vswz0 ^ (4 << 3);

    for (int it = 0; it < 32; ++it) {
        const int cur = it & 1;
        const _Float16* Kc = Kl[cur];
        const _Float16* Vc = Vt[cur];
        if (it + 1 < 32) {
            stageK(it + 1, Kl[cur ^ 1]);  // async, in flight across compute
            loadV(it + 1, va, vb);        // T14 issue-early
        }
        // ---- S'^T = K Q'^T (log2 domain)
        f32x16 st0 = {}, st1 = {};
#pragma unroll
        for (int dk = 0; dk < 4; dk++) {
            const int colr = 16 * dk + 8 * hi;
            half8 kf0 = *(const half8*)&Kc[l31 * 64 + (colr ^ kswz)];
            half8 kf1 = *(const half8*)&Kc[(32 + l31) * 64 + (colr ^ kswz)];
            __builtin_amdgcn_s_setprio(1);
            st0 = MFMA32(kf0, qf[dk], st0);
            st1 = MFMA32(kf1, qf[dk], st1);
            __builtin_amdgcn_s_setprio(0);
        }
        // ---- softmax numerator, no max tracking: p = 2^s', lane-local sum
        float lh = 0.f;
#pragma unroll
        for (int r = 0; r < 16; r++) { st0[r] = exp2f(st0[r]); lh += st0[r]; }
#pragma unroll
        for (int r = 0; r < 16; r++) { st1[r] = exp2f(st1[r]); lh += st1[r]; }
        lrun += lh;

        // ---- P fragments in-register (cvt_pkrtz + shfl_xor(32)) + PV
#define PV_CHUNK(stv, c)                                                                   \
        {                                                                                  \
            uint pk0 = __builtin_bit_cast(uint, __builtin_amdgcn_cvt_pkrtz(stv[(c & 1) * 8 + 0], stv[(c & 1) * 8 + 1])); \
            uint pk1 = __builtin_bit_cast(uint, __builtin_amdgcn_cvt_pkrtz(stv[(c & 1) * 8 + 2], stv[(c & 1) * 8 + 3])); \
            uint pk2 = __builtin_bit_cast(uint, __builtin_amdgcn_cvt_pkrtz(stv[(c & 1) * 8 + 4], stv[(c & 1) * 8 + 5])); \
            uint pk3 = __builtin_bit_cast(uint, __builtin_amdgcn_cvt_pkrtz(stv[(c & 1) * 8 + 6], stv[(c & 1) * 8 + 7])); \
            uint sa = __shfl_xor(pk0, 32), sb = __shfl_xor(pk1, 32);                       \
            uint sc = __shfl_xor(pk2, 32), sd = __shfl_xor(pk3, 32);                       \
            uint4v fu = {hi ? sc : pk0, hi ? sd : pk1, hi ? pk2 : sa, hi ? pk3 : sb};      \
            half8 pfrag = __builtin_bit_cast(half8, fu);                                   \
            const int colc = 16 * (c) + 8 * hi;                                            \
            half8 vf0 = *(const half8*)&Vc[l31 * 64 + (colc ^ vswz0)];                     \
            half8 vf1 = *(const half8*)&Vc[(32 + l31) * 64 + (colc ^ vswz1)];              \
            __builtin_amdgcn_s_setprio(1);                                                 \
            o0 = MFMA32(vf0, pfrag, o0);                                                   \
            o1 = MFMA32(vf1, pfrag, o1);                                                   \
            __builtin_amdgcn_s_setprio(0);                                                 \
        }
        PV_CHUNK(st0, 0)
        PV_CHUNK(st0, 1)
        PV_CHUNK(st1, 2)
        PV_CHUNK(st1, 3)
#undef PV_CHUNK

        if (it + 1 < 32) scatterV(va, vb, Vt[cur ^ 1]);
        __syncthreads();
    }

    // ---- epilogue: single cross-half reduce of l, then normalize + write
    lrun += __shfl_xor(lrun, 32);
    const float inv = __builtin_amdgcn_rcpf(lrun);
    const int tok = r0q + l31;
    _Float16* orow = out + (size_t)(b * 2048 + tok) * 1024 + h * 64;
#pragma unroll
    for (int g = 0; g < 4; g++) {
        half4 h4a, h4b;
#pragma unroll
        for (int j = 0; j < 4; j++) {
            h4a[j] = (_Float16)(o0[4 * g + j] * inv);
            h4b[j] = (_Float16)(o1[4 * g + j] * inv);
        }
        *(half4*)&orow[8 * g + 4 * hi] = h4a;
        *(half4*)&orow[32 + 8 * g + 4 * hi] = h4b;
    }
}

// ---------------------------------------------------------------- launch
extern "C" void kernel_launch(void* const* d_in, const int* in_sizes, int n_in,
                              void* d_out, int out_size, void* d_ws, size_t ws_size,
                              hipStream_t stream) {
    const float* x = (const float*)d_in[0];
    const float* w_qkv = (const float*)d_in[1];
    const float* b_qkv = (const float*)d_in[2];
    const float* q_gamma = (const float*)d_in[3];
    const float* q_beta = (const float*)d_in[4];
    const float* k_gamma = (const float*)d_in[5];
    const float* k_beta = (const float*)d_in[6];
    const float* w_proj = (const float*)d_in[7];
    const float* b_proj = (const float*)d_in[8];

    char* ws = (char*)d_ws;
    _Float16* xh = (_Float16*)(ws + 0);             // 4096*1024
    _Float16* wqkvh = (_Float16*)(ws + 8388608);    // 3072*1024
    _Float16* wprojh = (_Float16*)(ws + 14680064);  // 1024*1024
    _Float16* qkvh = (_Float16*)(ws + 16777216);    // 3*2*16*2048*64
    _Float16* attnh = (_Float16*)(ws + 41943040);   // 4096*1024

    cvt_all<<<4096, 256, 0, stream>>>(x, w_qkv, w_proj, xh, wqkvh, wprojh);

    gemm_nt<0><<<dim3(32, 24), 256, 0, stream>>>(xh, wqkvh, b_qkv, (void*)qkvh, 1024,
                                                 q_gamma, q_beta, k_gamma, k_beta);

    attn_kernel<<<512, 256, 0, stream>>>(qkvh, attnh);

    gemm_nt<1><<<dim3(32, 8), 256, 0, stream>>>(attnh, wprojh, b_proj, d_out, 1024,
                                                nullptr, nullptr, nullptr, nullptr);
}